// Round 5
// baseline (348.640 us; speedup 1.0000x reference)
//
#include <hip/hip_runtime.h>
#include <stdint.h>

#define N_NODES 50000
#define N_EDGES 800000
#define BCAP 128   // per-node bucket capacity; Poisson(16) tail beyond 128 ~ 1e-60
#define NSEG 8
#define SEGSZ 6250 // 50000/8 -> 3.2 MB feature-table slice per segment (512B rows)

typedef __attribute__((ext_vector_type(8))) short bf16x8;
typedef __attribute__((ext_vector_type(4))) float f32x4;

__device__ __forceinline__ float bf2f(unsigned short u) {
    return __builtin_bit_cast(float, (unsigned int)u << 16);
}
__device__ __forceinline__ unsigned short f2bf(float f) {  // RNE, finite inputs
    unsigned int u = __builtin_bit_cast(unsigned int, f);
    u += 0x7fffu + ((u >> 16) & 1u);
    return (unsigned short)(u >> 16);
}

__device__ __forceinline__ void load_lds16(const void* g, void* l) {
    __builtin_amdgcn_global_load_lds(
        (const __attribute__((address_space(1))) void*)(uintptr_t)g,
        (__attribute__((address_space(3))) void*)(unsigned int)(uintptr_t)l,
        16, 0, 0);
}

// ---------------- segmented bucket build: 3 passes, int atomics only ----------------
// Result: bucket[node*BCAP .. node*BCAP+deg) holds neighbor src ids sorted by
// src segment (src/SEGSZ). Every agg wave then sweeps addresses low->high in the
// same global order -> co-resident waves share a ~3.2MB working set (L2-resident).
__global__ __launch_bounds__(256) void count_k(
    const int* __restrict__ src, const int* __restrict__ dst,
    int* __restrict__ cnt8, int nedges)
{
    int e = blockIdx.x * 256 + threadIdx.x;
    if (e >= nedges) return;
    int d = dst[e], s = src[e];
    int seg = s / SEGSZ;
    atomicAdd(&cnt8[seg * N_NODES + d], 1);
}

__global__ __launch_bounds__(256) void offs_k(
    const int* __restrict__ cnt8, int* __restrict__ cur8,
    int* __restrict__ degtot, float* __restrict__ invdeg, int n)
{
    int i = blockIdx.x * 256 + threadIdx.x;
    if (i >= n) return;
    int run = 0;
#pragma unroll
    for (int s = 0; s < NSEG; s++) {
        cur8[s * N_NODES + i] = i * BCAP + run;
        run += cnt8[s * N_NODES + i];
    }
    degtot[i] = run;
    invdeg[i] = 1.0f / (float)(run > 1 ? run : 1);
}

__global__ __launch_bounds__(256) void scatter_k(
    const int* __restrict__ src, const int* __restrict__ dst,
    int* __restrict__ cur8, int* __restrict__ bucket, int nedges)
{
    int e = blockIdx.x * 256 + threadIdx.x;
    if (e >= nedges) return;
    int d = dst[e], s = src[e];
    int seg = s / SEGSZ;
    int p = atomicAdd(&cur8[seg * N_NODES + d], 1);
    if (p < d * BCAP + BCAP) bucket[p] = s;
}

// ---------------- converts ----------------
__global__ __launch_bounds__(256) void cvt_x_k(
    const float* __restrict__ x, unsigned short* __restrict__ dst)
{
    int tid = blockIdx.x * 256 + threadIdx.x;  // one per 4 floats
    if (tid >= N_NODES * 32) return;
    int row = tid >> 5, c = (tid & 31) * 4;
    float4 v = *(const float4*)(x + (size_t)row * 128 + c);
    ushort4 o;
    o.x = f2bf(v.x); o.y = f2bf(v.y); o.z = f2bf(v.z); o.w = f2bf(v.w);
    *(ushort4*)(dst + (size_t)row * 256 + 128 + c) = o;
}

__global__ __launch_bounds__(256) void cvt_w_k(
    const float* __restrict__ wl, const float* __restrict__ wr,
    unsigned short* __restrict__ dst, int Keach)
{
    int tid = blockIdx.x * 256 + threadIdx.x;
    if (tid >= 256 * 2 * Keach) return;
    int n = tid / (2 * Keach), k = tid - n * 2 * Keach;
    float v = (k < Keach) ? wl[(size_t)n * Keach + k]
                          : wr[(size_t)n * Keach + (k - Keach)];
    dst[tid] = f2bf(v);
}

// ---------------- aggregation: one wave per node, multi-edge vectorized gather ----
// Structure identical to R4 (correct, zero bank conflicts); bucket is now
// segment-sorted so all waves sweep the feature table in the same order.
__device__ __forceinline__ void acc8(float* a, uint4 u) {
    a[0] += bf2f((unsigned short)u.x); a[1] += bf2f((unsigned short)(u.x >> 16));
    a[2] += bf2f((unsigned short)u.y); a[3] += bf2f((unsigned short)(u.y >> 16));
    a[4] += bf2f((unsigned short)u.z); a[5] += bf2f((unsigned short)(u.z >> 16));
    a[6] += bf2f((unsigned short)u.w); a[7] += bf2f((unsigned short)(u.w >> 16));
}

template <int CPR>
__global__ __launch_bounds__(256) void agg_k(
    const unsigned short* __restrict__ feat, int featStride,  // stride in ushorts
    const int* __restrict__ bucket, const int* __restrict__ degtot,
    const float* __restrict__ invdeg,
    unsigned short* __restrict__ outmsg, int outStride, int nnodes)
{
    constexpr int E = 64 / CPR;
    int wv = threadIdx.x >> 6, lane = threadIdx.x & 63;
    int node = blockIdx.x * 4 + wv;
    if (node >= nnodes) return;
    int deg = degtot[node]; if (deg > BCAP) deg = BCAP;
    int idx0 = bucket[(size_t)node * BCAP + lane];
    int idx1 = bucket[(size_t)node * BCAP + 64 + lane];
    const int sub = lane / CPR;        // which edge within the group
    const int col = lane & (CPR - 1);  // which 16B chunk of the row

    float acc[8] = {};
    auto getsrc = [&](int e) -> int {  // REQUIRES full wave active
        return (e < 64) ? __shfl(idx0, e) : __shfl(idx1, e - 64);
    };
    auto rowp = [&](int s) -> const uint4* {
        return (const uint4*)(feat + (size_t)s * featStride + col * 8);
    };

    int j = 0;
    for (; j + 4 * E <= deg; j += 4 * E) {
        int s0 = getsrc(j + sub), s1 = getsrc(j + E + sub);
        int s2 = getsrc(j + 2 * E + sub), s3 = getsrc(j + 3 * E + sub);
        uint4 u0 = *rowp(s0), u1 = *rowp(s1), u2 = *rowp(s2), u3 = *rowp(s3);
        acc8(acc, u0); acc8(acc, u1); acc8(acc, u2); acc8(acc, u3);
    }
    for (; j + 2 * E <= deg; j += 2 * E) {
        int s0 = getsrc(j + sub), s1 = getsrc(j + E + sub);
        uint4 u0 = *rowp(s0), u1 = *rowp(s1);
        acc8(acc, u0); acc8(acc, u1);
    }
    for (; j + E <= deg; j += E) {
        uint4 u0 = *rowp(getsrc(j + sub));
        acc8(acc, u0);
    }
    if (j < deg) {                       // wave-uniform guard: all 64 lanes enter
        int e = j + sub;
        int ec = (e < deg) ? e : (deg - 1);   // clamp -> valid bucket slot
        uint4 u0 = *rowp(getsrc(ec));         // shfl with full wave active
        if (e < deg) acc8(acc, u0);           // predicate only the accumulate
    }

    // combine sub-groups: lanes with equal col hold partial sums (full wave active)
#pragma unroll
    for (int stride = 32; stride >= CPR; stride >>= 1) {
#pragma unroll
        for (int v = 0; v < 8; v++) acc[v] += __shfl_xor(acc[v], stride);
    }

    if (lane < CPR) {
        float s = invdeg[node];
        uint4 o;
        o.x = (unsigned int)f2bf(acc[0] * s) | ((unsigned int)f2bf(acc[1] * s) << 16);
        o.y = (unsigned int)f2bf(acc[2] * s) | ((unsigned int)f2bf(acc[3] * s) << 16);
        o.z = (unsigned int)f2bf(acc[4] * s) | ((unsigned int)f2bf(acc[5] * s) << 16);
        o.w = (unsigned int)f2bf(acc[6] * s) | ((unsigned int)f2bf(acc[7] * s) << 16);
        *(uint4*)(outmsg + (size_t)node * outStride + lane * 8) = o;
    }
}

// ---------------- bf16 MFMA GEMM: C = relu(A(MxK) * W(256xK)^T + bias) ----------------
// 128x128 block tile, 4 waves, each wave 32 rows x 128 cols via 2x8 16x16x32 MFMA tiles.
template <bool BF16OUT>
__global__ __launch_bounds__(256) void gemm_k(
    const unsigned short* __restrict__ A, const unsigned short* __restrict__ W,
    const float* __restrict__ bias, void* __restrict__ outp, int outStride,
    int M, int K)
{
    __shared__ __align__(16) char smem[(128 + 128) * 64];  // 16 KB
    const int t = threadIdx.x;
    const int w = t >> 6, lane = t & 63;
    const int quad = lane >> 4, l15 = lane & 15;
    const int row0 = blockIdx.x * 128;
    const int col0 = blockIdx.y * 128;

    f32x4 acc[2][8] = {};

    for (int ks = 0; ks < K; ks += 32) {
#pragma unroll
        for (int j = 0; j < 4; j++) {
            int call = w * 4 + j;        // 0..15, wave-uniform A/W split at 8
            int ci = call * 64 + lane;   // chunk id 0..1023
            const unsigned short* g;
            if (call < 8) {              // A chunks
                int rg = row0 + (ci >> 2);
                if (rg > M - 1) rg = M - 1;
                g = A + (size_t)rg * K + ks + (ci & 3) * 8;
            } else {                     // W chunks
                int c2 = ci - 512;
                g = W + (size_t)(col0 + (c2 >> 2)) * K + ks + (c2 & 3) * 8;
            }
            load_lds16(g, smem + ci * 16);
        }
        __syncthreads();

        const char* Ab = smem + (w * 32 + l15) * 64 + quad * 16;
        const char* Wb = smem + 8192 + l15 * 64 + quad * 16;
        bf16x8 af0 = *(const bf16x8*)(Ab);
        bf16x8 af1 = *(const bf16x8*)(Ab + 1024);
#pragma unroll
        for (int tt = 0; tt < 8; tt++) {
            bf16x8 bfr = *(const bf16x8*)(Wb + tt * 1024);
            acc[0][tt] = __builtin_amdgcn_mfma_f32_16x16x32_bf16(af0, bfr, acc[0][tt], 0, 0, 0);
            acc[1][tt] = __builtin_amdgcn_mfma_f32_16x16x32_bf16(af1, bfr, acc[1][tt], 0, 0, 0);
        }
        __syncthreads();
    }

#pragma unroll
    for (int g = 0; g < 2; g++) {
#pragma unroll
        for (int tt = 0; tt < 8; tt++) {
            int col = col0 + tt * 16 + l15;
            float bv = bias[col];
#pragma unroll
            for (int i = 0; i < 4; i++) {
                int row = row0 + w * 32 + g * 16 + quad * 4 + i;
                if (row < M) {
                    float v = fmaxf(acc[g][tt][i] + bv, 0.f);
                    size_t off = (size_t)row * outStride + col;
                    if constexpr (BF16OUT) ((unsigned short*)outp)[off] = f2bf(v);
                    else                   ((float*)outp)[off] = v;
                }
            }
        }
    }
}

extern "C" void kernel_launch(void* const* d_in, const int* in_sizes, int n_in,
                              void* d_out, int out_size, void* d_ws, size_t ws_size,
                              hipStream_t stream)
{
    const float* x   = (const float*)d_in[0];
    const int*   ei  = (const int*)d_in[1];
    const float* wl1 = (const float*)d_in[2];
    const float* bl1 = (const float*)d_in[3];
    const float* wr1 = (const float*)d_in[4];
    const float* wl2 = (const float*)d_in[5];
    const float* bl2 = (const float*)d_in[6];
    const float* wr2 = (const float*)d_in[7];
    float* out = (float*)d_out;
    const int* src = ei;
    const int* dst = ei + N_EDGES;

    char* ws = (char*)d_ws;
    size_t off = 0;
    auto alloc = [&](size_t bytes) -> void* {
        void* p = ws + off;
        off = (off + bytes + 255) & ~(size_t)255;
        return p;
    };
    int*            cnt8   = (int*)           alloc((size_t)NSEG * N_NODES * 4);  // 1.6 MB
    int*            cur8   = (int*)           alloc((size_t)NSEG * N_NODES * 4);  // 1.6 MB
    int*            degtot = (int*)           alloc((size_t)N_NODES * 4);
    int*            bucket = (int*)           alloc((size_t)N_NODES * BCAP * 4);  // 25.6 MB
    float*          invdeg = (float*)         alloc((size_t)N_NODES * 4);
    unsigned short* Acat1  = (unsigned short*)alloc((size_t)N_NODES * 256 * 2);   // [msg1|x]
    unsigned short* Acat2  = (unsigned short*)alloc((size_t)N_NODES * 512 * 2);   // [msg2|h]
    unsigned short* Wcat1  = (unsigned short*)alloc((size_t)256 * 256 * 2);
    unsigned short* Wcat2  = (unsigned short*)alloc((size_t)256 * 512 * 2);

    hipMemsetAsync(cnt8, 0, (size_t)NSEG * N_NODES * 4, stream);
    count_k<<<(N_EDGES + 255) / 256, 256, 0, stream>>>(src, dst, cnt8, N_EDGES);
    offs_k<<<(N_NODES + 255) / 256, 256, 0, stream>>>(cnt8, cur8, degtot, invdeg, N_NODES);
    scatter_k<<<(N_EDGES + 255) / 256, 256, 0, stream>>>(src, dst, cur8, bucket, N_EDGES);

    cvt_x_k<<<(N_NODES * 32 + 255) / 256, 256, 0, stream>>>(x, Acat1);
    cvt_w_k<<<(256 * 256 + 255) / 256, 256, 0, stream>>>(wl1, wr1, Wcat1, 128);
    cvt_w_k<<<(256 * 512 + 255) / 256, 256, 0, stream>>>(wl2, wr2, Wcat2, 256);

    // Layer 1: agg x_bf16 (256B rows, CPR=16) -> msg1; h -> right half of Acat2 (bf16)
    agg_k<16><<<(N_NODES + 3) / 4, 256, 0, stream>>>(
        Acat1 + 128, 256, bucket, degtot, invdeg, Acat1, 256, N_NODES);
    gemm_k<true><<<dim3((N_NODES + 127) / 128, 2), 256, 0, stream>>>(
        Acat1, Wcat1, bl1, (void*)(Acat2 + 256), 512, N_NODES, 256);

    // Layer 2: agg h (512B rows, CPR=32) -> msg2; out fp32
    agg_k<32><<<(N_NODES + 3) / 4, 256, 0, stream>>>(
        Acat2 + 256, 512, bucket, degtot, invdeg, Acat2, 512, N_NODES);
    gemm_k<false><<<dim3((N_NODES + 127) / 128, 2), 256, 0, stream>>>(
        Acat2, Wcat2, bl2, (void*)out, 256, N_NODES, 512);
}